// Round 5
// baseline (67.596 us; speedup 1.0000x reference)
//
#include <hip/hip_runtime.h>

#define NQ 8
#define NL 4
#define BATCH 4096

// ---------------------------------------------------------------------------
// Layout: one wave = 1 sample (256 amps). Amp a = (lane << 2) | r, r = 0..3.
// Wire i <-> bit (7 - i) of a (C-order flatten, wire 0 = MSB):
//   wire 0..5 <-> lane bits 5..0   (cross-lane)
//   wire 6,7  <-> reg  bits 1,0    (register ops)
// Cross-lane exchange per wire:
//   wire 0: xor32 -> __shfl_xor      wire 1: xor16 -> ds_swizzle 0x401F
//   wire 2: xor8  -> DPP row_ror:8   wire 3: xor4  -> ds_swizzle 0x101F
//   wire 4: xor2  -> DPP quad_perm   wire 5: xor1  -> DPP quad_perm
// Trig via raw v_sin_f32/v_cos_f32 (input in revolutions). All angles here
// are |t| <= pi/2 -> |rev| <= 0.25, no range reduction needed.
// ---------------------------------------------------------------------------

#define INV_2PI 0.15915494309189535f

__device__ __forceinline__ float fast_sin(float t) {   // sin(t), t in radians
  return __builtin_amdgcn_sinf(t * INV_2PI);
}
__device__ __forceinline__ float fast_cos(float t) {
  return __builtin_amdgcn_cosf(t * INV_2PI);
}

template <int CTRL>
__device__ __forceinline__ float dppx(float v) {
  return __int_as_float(
      __builtin_amdgcn_update_dpp(0, __float_as_int(v), CTRL, 0xF, 0xF, true));
}

template <int MASK>   // xor swizzle within 32-lane groups
__device__ __forceinline__ float swzx(float v) {
  return __int_as_float(
      __builtin_amdgcn_ds_swizzle(__float_as_int(v), (MASK << 10) | 0x1F));
}

__device__ __forceinline__ float xor32(float v) { return __shfl_xor(v, 32, 64); }

// exchange along lane-wire W (0..5): partner differs in lane bit (5 - W)
template <int W>
__device__ __forceinline__ float xl(float v) {
  if constexpr (W == 0) return xor32(v);
  else if constexpr (W == 1) return swzx<16>(v);
  else if constexpr (W == 2) return dppx<0x128>(v);   // row_ror:8 == lane^8
  else if constexpr (W == 3) return swzx<4>(v);
  else if constexpr (W == 4) return dppx<0x4E>(v);    // quad_perm [2,3,0,1] == ^2
  else return dppx<0xB1>(v);                          // quad_perm [1,0,3,2] == ^1
}

template <int W>
__device__ __forceinline__ void ry_gate(float re[4], float im[4],
                                        float c, float s, int lane) {
  if constexpr (W <= 5) {
    const float ss = ((lane >> (5 - W)) & 1) ? s : -s;
    float pr[4], pi[4];
#pragma unroll
    for (int r = 0; r < 4; ++r) { pr[r] = xl<W>(re[r]); pi[r] = xl<W>(im[r]); }
#pragma unroll
    for (int r = 0; r < 4; ++r) {
      re[r] = c * re[r] + ss * pr[r];
      im[r] = c * im[r] + ss * pi[r];
    }
  } else {
    constexpr int m = (W == 6) ? 2 : 1;
#pragma unroll
    for (int r = 0; r < 4; ++r) {
      if ((r & m) == 0) {
        const int r1 = r | m;
        float a0r = re[r], a1r = re[r1], a0i = im[r], a1i = im[r1];
        re[r]  = c * a0r - s * a1r;  re[r1] = s * a0r + c * a1r;
        im[r]  = c * a0i - s * a1i;  im[r1] = s * a0i + c * a1i;
      }
    }
  }
}

template <int W>
__device__ __forceinline__ void rz_gate(float re[4], float im[4],
                                        float c, float s, int lane) {
  // amp *= (c - i s) when wire-bit 0, (c + i s) when wire-bit 1
  if constexpr (W <= 5) {
    const float ss = ((lane >> (5 - W)) & 1) ? s : -s;
#pragma unroll
    for (int r = 0; r < 4; ++r) {
      float nr = re[r] * c - im[r] * ss;
      float ni = im[r] * c + re[r] * ss;
      re[r] = nr; im[r] = ni;
    }
  } else {
    constexpr int m = (W == 6) ? 2 : 1;
#pragma unroll
    for (int r = 0; r < 4; ++r) {
      const float ss = (r & m) ? s : -s;   // compile-time sign
      float nr = re[r] * c - im[r] * ss;
      float ni = im[r] * c + re[r] * ss;
      re[r] = nr; im[r] = ni;
    }
  }
}

// CNOT with lane-wire target W: lanes with ctrl bit set take their partner
template <int W>
__device__ __forceinline__ void cnot_lane(float re[4], float im[4], bool p) {
  float pr[4], pi[4];
#pragma unroll
  for (int r = 0; r < 4; ++r) { pr[r] = xl<W>(re[r]); pi[r] = xl<W>(im[r]); }
#pragma unroll
  for (int r = 0; r < 4; ++r) {
    re[r] = p ? pr[r] : re[r];
    im[r] = p ? pi[r] : im[r];
  }
}

__device__ __forceinline__ void cnot_ring(float re[4], float im[4], int lane) {
  cnot_lane<1>(re, im, (lane & 32) != 0);  // CNOT(0,1)
  cnot_lane<2>(re, im, (lane & 16) != 0);  // CNOT(1,2)
  cnot_lane<3>(re, im, (lane & 8) != 0);   // CNOT(2,3)
  cnot_lane<4>(re, im, (lane & 4) != 0);   // CNOT(3,4)
  cnot_lane<5>(re, im, (lane & 2) != 0);   // CNOT(4,5)
  // CNOT(5,6): ctrl lane bit0, tgt reg bit1 — predicated swap r0<->r2, r1<->r3
  {
    const bool p = (lane & 1) != 0;
#pragma unroll
    for (int r = 0; r < 2; ++r) {
      float t0 = re[r], t1 = re[r + 2];
      re[r] = p ? t1 : t0; re[r + 2] = p ? t0 : t1;
      t0 = im[r]; t1 = im[r + 2];
      im[r] = p ? t1 : t0; im[r + 2] = p ? t0 : t1;
    }
  }
  // CNOT(6,7): ctrl reg bit1, tgt reg bit0 — compile-time rename r2<->r3
  { float t = re[2]; re[2] = re[3]; re[3] = t;
    t = im[2]; im[2] = im[3]; im[3] = t; }
  // CNOT(7,0): ctrl reg bit0, tgt lane bit5 — odd regs take xor32 partner
  re[1] = xor32(re[1]); im[1] = xor32(im[1]);
  re[3] = xor32(re[3]); im[3] = xor32(im[3]);
}

__global__ __launch_bounds__(256) void vqc_kernel(const float* __restrict__ x,
                                                  const float* __restrict__ w,
                                                  float* __restrict__ out) {
  const int lane = (int)(threadIdx.x & 63);
  const int s = (int)((blockIdx.x * blockDim.x + threadIdx.x) >> 6);  // sample

  float re[4], im[4];
#pragma unroll
  for (int r = 0; r < 4; ++r) { re[r] = 0.f; im[r] = 0.f; }
  if (lane == 0) re[0] = 1.f;   // |0...0>

  // Angle encoding: RY(x_i) on wire i — batch all 8 sin/cos first (ILP)
  {
    const float4 x0 = *(const float4*)&x[s * 8];
    const float4 x1 = *(const float4*)&x[s * 8 + 4];
    const float t[8] = {x0.x, x0.y, x0.z, x0.w, x1.x, x1.y, x1.z, x1.w};
    float cs[8], sn[8];
#pragma unroll
    for (int i = 0; i < 8; ++i) {
      sn[i] = fast_sin(t[i] * 0.5f);
      cs[i] = fast_cos(t[i] * 0.5f);
    }
    ry_gate<0>(re, im, cs[0], sn[0], lane);
    ry_gate<1>(re, im, cs[1], sn[1], lane);
    ry_gate<2>(re, im, cs[2], sn[2], lane);
    ry_gate<3>(re, im, cs[3], sn[3], lane);
    ry_gate<4>(re, im, cs[4], sn[4], lane);
    ry_gate<5>(re, im, cs[5], sn[5], lane);
    ry_gate<6>(re, im, cs[6], sn[6], lane);
    ry_gate<7>(re, im, cs[7], sn[7], lane);
  }

#pragma unroll
  for (int l = 0; l < NL; ++l) {
    cnot_ring(re, im, lane);
    const float* wl = &w[l * NQ * 2];
    // batch all 16 angle evaluations for this layer (ILP over v_sin/v_cos)
    float cy[8], sy[8], cz[8], sz[8];
#pragma unroll
    for (int i = 0; i < 8; ++i) {
      float ty = wl[i * 2 + 0] * 0.5f;
      float tz = wl[i * 2 + 1] * 0.5f;
      sy[i] = fast_sin(ty); cy[i] = fast_cos(ty);
      sz[i] = fast_sin(tz); cz[i] = fast_cos(tz);
    }
    ry_gate<0>(re, im, cy[0], sy[0], lane); rz_gate<0>(re, im, cz[0], sz[0], lane);
    ry_gate<1>(re, im, cy[1], sy[1], lane); rz_gate<1>(re, im, cz[1], sz[1], lane);
    ry_gate<2>(re, im, cy[2], sy[2], lane); rz_gate<2>(re, im, cz[2], sz[2], lane);
    ry_gate<3>(re, im, cy[3], sy[3], lane); rz_gate<3>(re, im, cz[3], sz[3], lane);
    ry_gate<4>(re, im, cy[4], sy[4], lane); rz_gate<4>(re, im, cz[4], sz[4], lane);
    ry_gate<5>(re, im, cy[5], sy[5], lane); rz_gate<5>(re, im, cz[5], sz[5], lane);
    ry_gate<6>(re, im, cy[6], sy[6], lane); rz_gate<6>(re, im, cz[6], sz[6], lane);
    ry_gate<7>(re, im, cy[7], sy[7], lane); rz_gate<7>(re, im, cz[7], sz[7], lane);
  }

  // <Z_0>: wire 0 = amp bit 7 = lane bit 5
  float acc = 0.f;
#pragma unroll
  for (int r = 0; r < 4; ++r) acc += re[r] * re[r] + im[r] * im[r];
  acc = (lane & 32) ? -acc : acc;
  acc += dppx<0xB1>(acc);    // ^1
  acc += dppx<0x4E>(acc);    // ^2
  acc += swzx<4>(acc);       // ^4
  acc += dppx<0x128>(acc);   // ^8
  acc += swzx<16>(acc);      // ^16
  acc += xor32(acc);         // ^32
  if (lane == 0) out[s] = acc;
}

extern "C" void kernel_launch(void* const* d_in, const int* in_sizes, int n_in,
                              void* d_out, int out_size, void* d_ws, size_t ws_size,
                              hipStream_t stream) {
  const float* x = (const float*)d_in[0];   // (4096, 8) f32
  const float* w = (const float*)d_in[1];   // (4, 8, 2) f32
  float* out = (float*)d_out;               // (4096,) f32
  (void)in_sizes; (void)n_in; (void)out_size; (void)d_ws; (void)ws_size;

  // one wave per sample: 4096 waves = 1024 blocks x 256 threads, 4 waves/SIMD
  dim3 grid(BATCH / 4), block(256);
  hipLaunchKernelGGL(vqc_kernel, grid, block, 0, stream, x, w, out);
}

// Round 6
// 66.552 us; speedup vs baseline: 1.0157x; 1.0157x over previous
//
#include <hip/hip_runtime.h>

#define NQ 8
#define NL 4
#define BATCH 4096

// ---------------------------------------------------------------------------
// Layout: one wave = 2 samples. Lane bit 5 selects the sample; each 32-lane
// half holds its sample's 256 amps as 8 regs/lane:
//   amp a (b7..b0):  b7,b6,b5 = reg index bits 2,1,0;  b4..b0 = lane bits 4..0
// Wire i of the reference <-> amp bit (7-i):
//   wire 0..2 -> reg bits 2..0      (pure register ops)
//   wire 3    -> lane bit 4  xor16  (ds_swizzle 0x401F — the ONLY DS gate)
//   wire 4    -> lane bit 3  xor8   (DPP row_ror:8)
//   wire 5    -> lane bit 2  xor4   (DPP row_shl:4/row_shr:4 + select)
//   wire 6    -> lane bit 1  xor2   (DPP quad_perm [2,3,0,1])
//   wire 7    -> lane bit 0  xor1   (DPP quad_perm [1,0,3,2])
// 2048 waves = 2 waves/SIMD. Layer loop kept rolled to stay inside L1I.
// Trig: native v_sin/v_cos (rev input); all angles < pi/2, no range reduction.
// ---------------------------------------------------------------------------

#define INV_4PI 0.07957747154594767f   // rev(t/2) = t / (4*pi)

__device__ __forceinline__ float half_sin(float t) {  // sin(t/2)
  return __builtin_amdgcn_sinf(t * INV_4PI);
}
__device__ __forceinline__ float half_cos(float t) {  // cos(t/2)
  return __builtin_amdgcn_cosf(t * INV_4PI);
}

template <int CTRL>
__device__ __forceinline__ float dppx(float v) {
  return __int_as_float(
      __builtin_amdgcn_update_dpp(0, __float_as_int(v), CTRL, 0xF, 0xF, true));
}

template <int MASK>   // xor swizzle within 32-lane groups (sample = 32 lanes)
__device__ __forceinline__ float swzx(float v) {
  return __int_as_float(
      __builtin_amdgcn_ds_swizzle(__float_as_int(v), (MASK << 10) | 0x1F));
}

// exchange along lane-wire W (3..7): partner lane = lane ^ (1 << (7-W))
template <int W>
__device__ __forceinline__ float xl(float v, int lane) {
  if constexpr (W == 3) return swzx<16>(v);
  else if constexpr (W == 4) return dppx<0x128>(v);          // row_ror:8 == ^8
  else if constexpr (W == 5) {
    // xor4 without DS: lanes with bit2=0 need lane+4 (row_shl:4),
    // bit2=1 need lane-4 (row_shr:4); bound_ctrl zeros are never selected.
    float lo = dppx<0x104>(v);   // row_shl:4 : lane i <- i+4
    float hi = dppx<0x114>(v);   // row_shr:4 : lane i <- i-4
    return (lane & 4) ? hi : lo;
  }
  else if constexpr (W == 6) return dppx<0x4E>(v);           // quad ^2
  else return dppx<0xB1>(v);                                 // quad ^1
}

// ---- RY -------------------------------------------------------------------
template <int W>   // reg wire, W in 0..2, pair mask m over reg index
__device__ __forceinline__ void ry_reg(float re[8], float im[8], float c, float s) {
  constexpr int m = 4 >> W;
#pragma unroll
  for (int r = 0; r < 8; ++r) {
    if ((r & m) == 0) {
      const int r1 = r | m;
      float a0r = re[r], a1r = re[r1], a0i = im[r], a1i = im[r1];
      re[r]  = c * a0r - s * a1r;  re[r1] = s * a0r + c * a1r;
      im[r]  = c * a0i - s * a1i;  im[r1] = s * a0i + c * a1i;
    }
  }
}

template <int W>   // lane wire, W in 3..7
__device__ __forceinline__ void ry_lane(float re[8], float im[8],
                                        float c, float s, int lane) {
  const float ss = ((lane >> (7 - W)) & 1) ? s : -s;
#pragma unroll
  for (int r = 0; r < 8; ++r) {
    float pr = xl<W>(re[r], lane);
    float pi = xl<W>(im[r], lane);
    re[r] = c * re[r] + ss * pr;
    im[r] = c * im[r] + ss * pi;
  }
}

// ---- RZ -------------------------------------------------------------------
template <int W>   // reg wire
__device__ __forceinline__ void rz_reg(float re[8], float im[8], float c, float s) {
  constexpr int m = 4 >> W;
#pragma unroll
  for (int r = 0; r < 8; ++r) {
    const float ss = (r & m) ? s : -s;   // compile-time sign
    float nr = c * re[r] - ss * im[r];
    float ni = c * im[r] + ss * re[r];
    re[r] = nr; im[r] = ni;
  }
}

template <int W>   // lane wire
__device__ __forceinline__ void rz_lane(float re[8], float im[8],
                                        float c, float s, int lane) {
  const float ss = ((lane >> (7 - W)) & 1) ? s : -s;
#pragma unroll
  for (int r = 0; r < 8; ++r) {
    float nr = c * re[r] - ss * im[r];
    float ni = c * im[r] + ss * re[r];
    re[r] = nr; im[r] = ni;
  }
}

// ---- CNOT ring ------------------------------------------------------------
template <int W>   // lane-wire target: ctrl-true lanes take their partner
__device__ __forceinline__ void cnot_lane(float re[8], float im[8],
                                          bool p, int lane) {
#pragma unroll
  for (int r = 0; r < 8; ++r) {
    float pr = xl<W>(re[r], lane);
    float pi = xl<W>(im[r], lane);
    re[r] = p ? pr : re[r];
    im[r] = p ? pi : im[r];
  }
}

__device__ __forceinline__ void cnot_ring(float re[8], float im[8], int lane) {
  // CNOT(0,1): ctrl reg bit2, tgt reg bit1 -> swap r4<->r6, r5<->r7
  { float t;
    t = re[4]; re[4] = re[6]; re[6] = t;  t = im[4]; im[4] = im[6]; im[6] = t;
    t = re[5]; re[5] = re[7]; re[7] = t;  t = im[5]; im[5] = im[7]; im[7] = t; }
  // CNOT(1,2): ctrl reg bit1, tgt reg bit0 -> swap r2<->r3, r6<->r7
  { float t;
    t = re[2]; re[2] = re[3]; re[3] = t;  t = im[2]; im[2] = im[3]; im[3] = t;
    t = re[6]; re[6] = re[7]; re[7] = t;  t = im[6]; im[6] = im[7]; im[7] = t; }
  // CNOT(2,3): ctrl reg bit0 (odd regs), tgt lane bit4 -> odd regs xor16
#pragma unroll
  for (int r = 1; r < 8; r += 2) {
    re[r] = swzx<16>(re[r]);
    im[r] = swzx<16>(im[r]);
  }
  // CNOT(3,4): ctrl lane bit4, tgt lane bit3
  cnot_lane<4>(re, im, (lane & 16) != 0, lane);
  // CNOT(4,5): ctrl lane bit3, tgt lane bit2
  cnot_lane<5>(re, im, (lane & 8) != 0, lane);
  // CNOT(5,6): ctrl lane bit2, tgt lane bit1
  cnot_lane<6>(re, im, (lane & 4) != 0, lane);
  // CNOT(6,7): ctrl lane bit1, tgt lane bit0
  cnot_lane<7>(re, im, (lane & 2) != 0, lane);
  // CNOT(7,0): ctrl lane bit0, tgt reg bit2 -> predicated swap (r, r+4)
  {
    const bool p = (lane & 1) != 0;
#pragma unroll
    for (int r = 0; r < 4; ++r) {
      float t0 = re[r], t1 = re[r + 4];
      re[r] = p ? t1 : t0; re[r + 4] = p ? t0 : t1;
      t0 = im[r]; t1 = im[r + 4];
      im[r] = p ? t1 : t0; im[r + 4] = p ? t0 : t1;
    }
  }
}

// ---------------------------------------------------------------------------
__global__ __launch_bounds__(256) void vqc_kernel(const float* __restrict__ x,
                                                  const float* __restrict__ w,
                                                  float* __restrict__ out) {
  const int lane = (int)(threadIdx.x & 63);
  const int wv = (int)((blockIdx.x * blockDim.x + threadIdx.x) >> 6);
  const int s = wv * 2 + (lane >> 5);   // this half-wave's sample

  float re[8], im[8];
#pragma unroll
  for (int r = 0; r < 8; ++r) { re[r] = 0.f; im[r] = 0.f; }
  if ((lane & 31) == 0) re[0] = 1.f;    // |0...0>

  // Angle encoding: RY(x_i) on wire i
  {
    const float4 x0 = *(const float4*)&x[s * 8];
    const float4 x1 = *(const float4*)&x[s * 8 + 4];
    const float t[8] = {x0.x, x0.y, x0.z, x0.w, x1.x, x1.y, x1.z, x1.w};
    float cs[8], sn[8];
#pragma unroll
    for (int i = 0; i < 8; ++i) { sn[i] = half_sin(t[i]); cs[i] = half_cos(t[i]); }
    ry_reg<0>(re, im, cs[0], sn[0]);
    ry_reg<1>(re, im, cs[1], sn[1]);
    ry_reg<2>(re, im, cs[2], sn[2]);
    ry_lane<3>(re, im, cs[3], sn[3], lane);
    ry_lane<4>(re, im, cs[4], sn[4], lane);
    ry_lane<5>(re, im, cs[5], sn[5], lane);
    ry_lane<6>(re, im, cs[6], sn[6], lane);
    ry_lane<7>(re, im, cs[7], sn[7], lane);
  }

  // Variational layers — rolled loop (code size: keep L1I resident)
#pragma unroll 1
  for (int l = 0; l < NL; ++l) {
    cnot_ring(re, im, lane);
    const float* wl = &w[l * NQ * 2];
    float cy[8], sy[8], cz[8], sz[8];
#pragma unroll
    for (int i = 0; i < 8; ++i) {
      float ty = wl[i * 2 + 0];
      float tz = wl[i * 2 + 1];
      sy[i] = half_sin(ty); cy[i] = half_cos(ty);
      sz[i] = half_sin(tz); cz[i] = half_cos(tz);
    }
    ry_reg<0>(re, im, cy[0], sy[0]);        rz_reg<0>(re, im, cz[0], sz[0]);
    ry_reg<1>(re, im, cy[1], sy[1]);        rz_reg<1>(re, im, cz[1], sz[1]);
    ry_reg<2>(re, im, cy[2], sy[2]);        rz_reg<2>(re, im, cz[2], sz[2]);
    ry_lane<3>(re, im, cy[3], sy[3], lane); rz_lane<3>(re, im, cz[3], sz[3], lane);
    ry_lane<4>(re, im, cy[4], sy[4], lane); rz_lane<4>(re, im, cz[4], sz[4], lane);
    ry_lane<5>(re, im, cy[5], sy[5], lane); rz_lane<5>(re, im, cz[5], sz[5], lane);
    ry_lane<6>(re, im, cy[6], sy[6], lane); rz_lane<6>(re, im, cz[6], sz[6], lane);
    ry_lane<7>(re, im, cy[7], sy[7], lane); rz_lane<7>(re, im, cz[7], sz[7], lane);
  }

  // <Z_0>: wire 0 = amp bit 7 = reg bit 2 -> sign per register, then reduce
  // over the sample's 32 lanes.
  float acc = 0.f;
#pragma unroll
  for (int r = 0; r < 8; ++r) {
    float m2 = re[r] * re[r] + im[r] * im[r];
    acc += (r & 4) ? -m2 : m2;
  }
  acc += dppx<0xB1>(acc);    // ^1
  acc += dppx<0x4E>(acc);    // ^2
  acc += swzx<4>(acc);       // ^4
  acc += dppx<0x128>(acc);   // ^8
  acc += swzx<16>(acc);      // ^16
  if ((lane & 31) == 0) out[s] = acc;
}

extern "C" void kernel_launch(void* const* d_in, const int* in_sizes, int n_in,
                              void* d_out, int out_size, void* d_ws, size_t ws_size,
                              hipStream_t stream) {
  const float* x = (const float*)d_in[0];   // (4096, 8) f32
  const float* w = (const float*)d_in[1];   // (4, 8, 2) f32
  float* out = (float*)d_out;               // (4096,) f32
  (void)in_sizes; (void)n_in; (void)out_size; (void)d_ws; (void)ws_size;

  // two samples per wave: 2048 waves = 512 blocks x 256 threads, 2 waves/SIMD
  dim3 grid(BATCH / 8), block(256);
  hipLaunchKernelGGL(vqc_kernel, grid, block, 0, stream, x, w, out);
}

// Round 7
// 66.312 us; speedup vs baseline: 1.0194x; 1.0036x over previous
//
#include <hip/hip_runtime.h>

#define NQ 8
#define NL 4
#define BATCH 4096

// ---------------------------------------------------------------------------
// Layout: one wave = 2 samples. Lane bit 5 selects the sample; each 32-lane
// half holds its sample's 256 amps as 8 float2 (re,im) regs/lane:
//   amp a (b7..b0):  b7,b6,b5 = reg index bits 2,1,0;  b4..b0 = lane bits 4..0
// Wire i of the reference <-> amp bit (7-i):
//   wire 0..2 -> reg bits 2..0      (pure register ops)
//   wire 3    -> lane bit 4  xor16  (ds_swizzle 0x401F)
//   wire 4    -> lane bit 3  xor8   (DPP row_ror:8)
//   wire 5    -> lane bit 2  xor4   (ds_swizzle 0x101F)
//   wire 6    -> lane bit 1  xor2   (DPP quad_perm [2,3,0,1])
//   wire 7    -> lane bit 0  xor1   (DPP quad_perm [1,0,3,2])
// State held as float2 so RY/RZ arithmetic dual-issues as v_pk_fma_f32
// (same coefficients applied to re and im). 2048 waves = 2 waves/SIMD.
// Trig: native v_sin/v_cos (rev input); all angles < pi/2, no range reduction.
// ---------------------------------------------------------------------------

#define INV_4PI 0.07957747154594767f   // rev(t/2) = t / (4*pi)

__device__ __forceinline__ float half_sin(float t) {  // sin(t/2)
  return __builtin_amdgcn_sinf(t * INV_4PI);
}
__device__ __forceinline__ float half_cos(float t) {  // cos(t/2)
  return __builtin_amdgcn_cosf(t * INV_4PI);
}

template <int CTRL>
__device__ __forceinline__ float dppx(float v) {
  return __int_as_float(
      __builtin_amdgcn_update_dpp(0, __float_as_int(v), CTRL, 0xF, 0xF, true));
}

template <int MASK>   // xor swizzle within 32-lane groups (sample = 32 lanes)
__device__ __forceinline__ float swzx(float v) {
  return __int_as_float(
      __builtin_amdgcn_ds_swizzle(__float_as_int(v), (MASK << 10) | 0x1F));
}

// exchange along lane-wire W (3..7) on a packed (re,im) pair
template <int W>
__device__ __forceinline__ float2 xl2(float2 v) {
  float2 r;
  if constexpr (W == 3)      { r.x = swzx<16>(v.x);    r.y = swzx<16>(v.y); }
  else if constexpr (W == 4) { r.x = dppx<0x128>(v.x); r.y = dppx<0x128>(v.y); }
  else if constexpr (W == 5) { r.x = swzx<4>(v.x);     r.y = swzx<4>(v.y); }
  else if constexpr (W == 6) { r.x = dppx<0x4E>(v.x);  r.y = dppx<0x4E>(v.y); }
  else                       { r.x = dppx<0xB1>(v.x);  r.y = dppx<0xB1>(v.y); }
  return r;
}

// ---- RY -------------------------------------------------------------------
template <int W>   // reg wire, W in 0..2
__device__ __forceinline__ void ry_reg(float2 ri[8], float c, float s) {
  constexpr int m = 4 >> W;
#pragma unroll
  for (int r = 0; r < 8; ++r) {
    if ((r & m) == 0) {
      const int r1 = r | m;
      float2 a0 = ri[r], a1 = ri[r1];
      ri[r].x  = c * a0.x - s * a1.x;  ri[r].y  = c * a0.y - s * a1.y;
      ri[r1].x = s * a0.x + c * a1.x;  ri[r1].y = s * a0.y + c * a1.y;
    }
  }
}

template <int W>   // lane wire, W in 3..7
__device__ __forceinline__ void ry_lane(float2 ri[8], float c, float s, int lane) {
  const float ss = ((lane >> (7 - W)) & 1) ? s : -s;
#pragma unroll
  for (int r = 0; r < 8; ++r) {
    float2 p = xl2<W>(ri[r]);
    ri[r].x = c * ri[r].x + ss * p.x;   // packs: v_pk_mul + v_pk_fma
    ri[r].y = c * ri[r].y + ss * p.y;
  }
}

// ---- RZ -------------------------------------------------------------------
template <int W>   // reg wire
__device__ __forceinline__ void rz_reg(float2 ri[8], float c, float s) {
  constexpr int m = 4 >> W;
#pragma unroll
  for (int r = 0; r < 8; ++r) {
    const float ss = (r & m) ? s : -s;   // compile-time sign
    float2 a = ri[r];
    ri[r].x = c * a.x - ss * a.y;
    ri[r].y = c * a.y + ss * a.x;
  }
}

template <int W>   // lane wire
__device__ __forceinline__ void rz_lane(float2 ri[8], float c, float s, int lane) {
  const float ss = ((lane >> (7 - W)) & 1) ? s : -s;
#pragma unroll
  for (int r = 0; r < 8; ++r) {
    float2 a = ri[r];
    ri[r].x = c * a.x - ss * a.y;
    ri[r].y = c * a.y + ss * a.x;
  }
}

// ---- CNOT ring ------------------------------------------------------------
template <int W>   // lane-wire target: ctrl-true lanes take their partner
__device__ __forceinline__ void cnot_lane(float2 ri[8], bool p) {
#pragma unroll
  for (int r = 0; r < 8; ++r) {
    float2 pp = xl2<W>(ri[r]);
    ri[r].x = p ? pp.x : ri[r].x;
    ri[r].y = p ? pp.y : ri[r].y;
  }
}

__device__ __forceinline__ void cnot_ring(float2 ri[8], int lane) {
  // CNOT(0,1): ctrl reg bit2, tgt reg bit1 -> swap r4<->r6, r5<->r7
  { float2 t;
    t = ri[4]; ri[4] = ri[6]; ri[6] = t;
    t = ri[5]; ri[5] = ri[7]; ri[7] = t; }
  // CNOT(1,2): ctrl reg bit1, tgt reg bit0 -> swap r2<->r3, r6<->r7
  { float2 t;
    t = ri[2]; ri[2] = ri[3]; ri[3] = t;
    t = ri[6]; ri[6] = ri[7]; ri[7] = t; }
  // CNOT(2,3): ctrl reg bit0 (odd regs), tgt lane bit4 -> odd regs xor16
#pragma unroll
  for (int r = 1; r < 8; r += 2) {
    ri[r].x = swzx<16>(ri[r].x);
    ri[r].y = swzx<16>(ri[r].y);
  }
  // CNOT(3,4): ctrl lane bit4, tgt lane bit3
  cnot_lane<4>(ri, (lane & 16) != 0);
  // CNOT(4,5): ctrl lane bit3, tgt lane bit2
  cnot_lane<5>(ri, (lane & 8) != 0);
  // CNOT(5,6): ctrl lane bit2, tgt lane bit1
  cnot_lane<6>(ri, (lane & 4) != 0);
  // CNOT(6,7): ctrl lane bit1, tgt lane bit0
  cnot_lane<7>(ri, (lane & 2) != 0);
  // CNOT(7,0): ctrl lane bit0, tgt reg bit2 -> predicated swap (r, r+4)
  {
    const bool p = (lane & 1) != 0;
#pragma unroll
    for (int r = 0; r < 4; ++r) {
      float2 t0 = ri[r], t1 = ri[r + 4];
      ri[r].x = p ? t1.x : t0.x;      ri[r].y = p ? t1.y : t0.y;
      ri[r + 4].x = p ? t0.x : t1.x;  ri[r + 4].y = p ? t0.y : t1.y;
    }
  }
}

// ---------------------------------------------------------------------------
__global__ __launch_bounds__(256) void vqc_kernel(const float* __restrict__ x,
                                                  const float* __restrict__ w,
                                                  float* __restrict__ out) {
  const int lane = (int)(threadIdx.x & 63);
  const int wv = (int)((blockIdx.x * blockDim.x + threadIdx.x) >> 6);
  const int s = wv * 2 + (lane >> 5);   // this half-wave's sample

  float2 ri[8];
#pragma unroll
  for (int r = 0; r < 8; ++r) ri[r] = make_float2(0.f, 0.f);
  if ((lane & 31) == 0) ri[0].x = 1.f;  // |0...0>

  // Angle encoding: RY(x_i) on wire i
  {
    const float4 x0 = *(const float4*)&x[s * 8];
    const float4 x1 = *(const float4*)&x[s * 8 + 4];
    const float t[8] = {x0.x, x0.y, x0.z, x0.w, x1.x, x1.y, x1.z, x1.w};
    float cs[8], sn[8];
#pragma unroll
    for (int i = 0; i < 8; ++i) { sn[i] = half_sin(t[i]); cs[i] = half_cos(t[i]); }
    ry_reg<0>(ri, cs[0], sn[0]);
    ry_reg<1>(ri, cs[1], sn[1]);
    ry_reg<2>(ri, cs[2], sn[2]);
    ry_lane<3>(ri, cs[3], sn[3], lane);
    ry_lane<4>(ri, cs[4], sn[4], lane);
    ry_lane<5>(ri, cs[5], sn[5], lane);
    ry_lane<6>(ri, cs[6], sn[6], lane);
    ry_lane<7>(ri, cs[7], sn[7], lane);
  }

  // Variational layers — rolled loop (keep L1I resident)
#pragma unroll 1
  for (int l = 0; l < NL; ++l) {
    cnot_ring(ri, lane);
    const float* wl = &w[l * NQ * 2];
    float cy[8], sy[8], cz[8], sz[8];
#pragma unroll
    for (int i = 0; i < 8; ++i) {
      float ty = wl[i * 2 + 0];
      float tz = wl[i * 2 + 1];
      sy[i] = half_sin(ty); cy[i] = half_cos(ty);
      sz[i] = half_sin(tz); cz[i] = half_cos(tz);
    }
    ry_reg<0>(ri, cy[0], sy[0]);        rz_reg<0>(ri, cz[0], sz[0]);
    ry_reg<1>(ri, cy[1], sy[1]);        rz_reg<1>(ri, cz[1], sz[1]);
    ry_reg<2>(ri, cy[2], sy[2]);        rz_reg<2>(ri, cz[2], sz[2]);
    ry_lane<3>(ri, cy[3], sy[3], lane); rz_lane<3>(ri, cz[3], sz[3], lane);
    ry_lane<4>(ri, cy[4], sy[4], lane); rz_lane<4>(ri, cz[4], sz[4], lane);
    ry_lane<5>(ri, cy[5], sy[5], lane); rz_lane<5>(ri, cz[5], sz[5], lane);
    ry_lane<6>(ri, cy[6], sy[6], lane); rz_lane<6>(ri, cz[6], sz[6], lane);
    ry_lane<7>(ri, cy[7], sy[7], lane); rz_lane<7>(ri, cz[7], sz[7], lane);
  }

  // <Z_0>: wire 0 = amp bit 7 = reg bit 2 -> sign per register, then reduce
  // over the sample's 32 lanes.
  float acc = 0.f;
#pragma unroll
  for (int r = 0; r < 8; ++r) {
    float m2 = ri[r].x * ri[r].x + ri[r].y * ri[r].y;
    acc += (r & 4) ? -m2 : m2;
  }
  acc += dppx<0xB1>(acc);    // ^1
  acc += dppx<0x4E>(acc);    // ^2
  acc += swzx<4>(acc);       // ^4
  acc += dppx<0x128>(acc);   // ^8
  acc += swzx<16>(acc);      // ^16
  if ((lane & 31) == 0) out[s] = acc;
}

extern "C" void kernel_launch(void* const* d_in, const int* in_sizes, int n_in,
                              void* d_out, int out_size, void* d_ws, size_t ws_size,
                              hipStream_t stream) {
  const float* x = (const float*)d_in[0];   // (4096, 8) f32
  const float* w = (const float*)d_in[1];   // (4, 8, 2) f32
  float* out = (float*)d_out;               // (4096,) f32
  (void)in_sizes; (void)n_in; (void)out_size; (void)d_ws; (void)ws_size;

  // two samples per wave: 2048 waves = 512 blocks x 256 threads, 2 waves/SIMD
  dim3 grid(BATCH / 8), block(256);
  hipLaunchKernelGGL(vqc_kernel, grid, block, 0, stream, x, w, out);
}